// Round 1
// 311.904 us; speedup vs baseline: 1.0727x; 1.0727x over previous
//
#include <hip/hip_runtime.h>
#include <hip/hip_bf16.h>
#include <math.h>

#define N_NODES 50000
#define E0      800000
#define E_TOT   (E0 + N_NODES)
#define SCAP    512

using bf16 = __hip_bfloat16;
typedef __attribute__((ext_vector_type(8))) short bfrag;   // 8 bf16 (4 VGPRs)
typedef __attribute__((ext_vector_type(4))) float ffrag;   // 4 fp32 acc

static __device__ __forceinline__ float bfu2f_lo(unsigned u){ return __uint_as_float(u << 16); }
static __device__ __forceinline__ float bfu2f_hi(unsigned u){ return __uint_as_float(u & 0xffff0000u); }

static __device__ __forceinline__ unsigned packbf(float a, float b){
    bf16 x = __float2bfloat16(a), y = __float2bfloat16(b);
    unsigned short ux = *reinterpret_cast<unsigned short*>(&x);
    unsigned short uy = *reinterpret_cast<unsigned short*>(&y);
    return ((unsigned)uy << 16) | ux;
}

// per-wave dtype detects (one coalesced load + ballot)
static __device__ __forceinline__ int detect_f32(const unsigned* xu){
    int lane = threadIdx.x & 63;
    unsigned ex = (xu[lane] >> 7) & 0xFF;
    return (__ballot(ex < 100 || ex > 140) != 0ULL);
}
static __device__ __forceinline__ int detect_i32(const int* ei){
    int lane = threadIdx.x & 63;
    return (__ballot(ei[2 * lane + 1] != 0) != 0ULL);
}

static __device__ __forceinline__ float ldany(const void* p, int i, int isf32){
    return isf32 ? ((const float*)p)[i] : __bfloat162float(((const bf16*)p)[i]);
}

// ---------------- convert: W1/Wg/W3 -> packed bf16 MFMA frags, vecs->fp32,
// x->bf16, zero deg — one grid.
// vecf: b1 @0(128), bg @128(64), b3 @192(64), att_s @256(128), att_d @384(128)
__global__ void k_convert(const void* __restrict__ xv,
                          const void* W1, const void* Wg, const void* W3,
                          const void* b1, const void* bg, const void* b3,
                          const void* as_, const void* ad_,
                          bf16* __restrict__ W1p, bf16* __restrict__ Wgp,
                          bf16* __restrict__ W3p, float* __restrict__ vecf,
                          bf16* __restrict__ xb, int* __restrict__ deg){
    const int NXB = (N_NODES * 128 + 255) / 256;
    int b = blockIdx.x, t = threadIdx.x;
    if (b >= 148 + NXB){
        int i = (b - 148 - NXB) * 256 + t;
        if (i < N_NODES) deg[i] = 0;
        return;
    }
    int isf = detect_f32((const unsigned*)xv);
    if (b >= 148){
        int i = (b - 148) * 256 + t;
        if (i < N_NODES * 128) xb[i] = __float2bfloat16(ldany(xv, i, isf));
        return;
    }
    if (b < 16){                              // W3 pack: 4096 elems
        int dd = b * 256 + t;
        int j  = dd & 7;
        int L  = (dd >> 3) & 63;
        int kc = (dd >> 9) & 1;
        int ct = dd >> 10;
        int k = kc * 32 + ((L >> 4) << 3) + j;
        int n = ct * 16 + (L & 15);
        W3p[dd] = __float2bfloat16(ldany(W3, k * 64 + n, isf));
    }
    else if (b < 18){
        int i = (b - 16) * 256 + t;     // 0..511
        float v;
        if      (i < 128) v = ldany(b1,  i,       isf);
        else if (i < 192) v = ldany(bg,  i - 128, isf);
        else if (i < 256) v = ldany(b3,  i - 192, isf);
        else if (i < 384) v = ldany(as_, i - 256, isf);
        else              v = ldany(ad_, i - 384, isf);
        vecf[i] = v;
    } else {
        int d = (b - 18) * 256 + t;          // 0..16383 per W, two Ws
        const void* Wsrc = (d < 16384) ? W1 : Wg;
        bf16* Wdst = (d < 16384) ? W1p : Wgp;
        int dd = d & 16383;
        int j  = dd & 7;
        int L  = (dd >> 3) & 63;
        int kc = (dd >> 9) & 3;
        int ct = dd >> 11;
        int k = kc * 32 + ((L >> 4) << 3) + j;
        int n = ct * 16 + (L & 15);
        Wdst[dd] = __float2bfloat16(ldany(Wsrc, k * 128 + n, isf));
    }
}

// ---------------- CSR build ----------------

static __device__ __forceinline__ int load_dst(const int* ei, int e, int is32){
    if (e >= E0) return e - E0;
    return is32 ? ei[E0 + e] : (int)((const long long*)ei)[E0 + e];
}
static __device__ __forceinline__ int load_src(const int* ei, int e, int is32){
    if (e >= E0) return e - E0;
    return is32 ? ei[e] : (int)((const long long*)ei)[e];
}

// count degrees AND capture each edge's rank within its dst bucket (streaming store).
// The atomic's return value is exactly the slot k_fill needs -> k_fill needs NO atomics.
__global__ void k_count(const int* __restrict__ ei, int* __restrict__ deg,
                        int* __restrict__ rank){
    int is32 = detect_i32(ei);
    int e = blockIdx.x * blockDim.x + threadIdx.x;
    if (e >= E_TOT) return;
    int dst = load_dst(ei, e, is32);
    int src = load_src(ei, e, is32);
    if ((unsigned)dst >= N_NODES || (unsigned)src >= N_NODES) return;
    rank[e] = atomicAdd(&deg[dst], 1);
}

__global__ void k_scanA(const int* __restrict__ deg, int* __restrict__ tmp, int* __restrict__ blk){
    __shared__ int s[256];
    int t = threadIdx.x;
    int i = blockIdx.x * 256 + t;
    int v = (i < N_NODES) ? deg[i] : 0;
    s[t] = v; __syncthreads();
    for (int off = 1; off < 256; off <<= 1){
        int x = (t >= off) ? s[t - off] : 0;
        __syncthreads();
        s[t] += x;
        __syncthreads();
    }
    if (t == 255) blk[blockIdx.x] = s[255];
    if (i < N_NODES) tmp[i] = s[t] - v;
}

__global__ void k_scanB(int* __restrict__ blk, int nb){
    __shared__ int s[256];
    int t = threadIdx.x;
    int v = (t < nb) ? blk[t] : 0;
    s[t] = v; __syncthreads();
    for (int off = 1; off < 256; off <<= 1){
        int x = (t >= off) ? s[t - off] : 0;
        __syncthreads();
        s[t] += x;
        __syncthreads();
    }
    if (t < nb) blk[t] = s[t] - v;
}

__global__ void k_scanC(int* __restrict__ row_ptr, const int* __restrict__ blk,
                        const int* __restrict__ deg, float* __restrict__ inv_sqrt){
    int i = blockIdx.x * blockDim.x + threadIdx.x;
    if (i < N_NODES){
        row_ptr[i] += blk[i >> 8];
        int d = deg[i];
        inv_sqrt[i] = (d > 0) ? rsqrtf((float)d) : 0.0f;
    }
    if (i == 0) row_ptr[N_NODES] = E_TOT;
}

// fill: NO atomics (rank precomputed); ONE scattered 8B store per edge
// (src + coef packed as int2) instead of two scattered 4B stores.
__global__ void k_fill(const int* __restrict__ ei, const int* __restrict__ row_ptr,
                       const float* __restrict__ isq, const int* __restrict__ rank,
                       int2* __restrict__ ecr){
    int is32 = detect_i32(ei);
    int e = blockIdx.x * blockDim.x + threadIdx.x;
    if (e >= E_TOT) return;
    int dst = load_dst(ei, e, is32);
    int src = load_src(ei, e, is32);
    if ((unsigned)dst >= N_NODES || (unsigned)src >= N_NODES) return;
    int pos = row_ptr[dst] + rank[e];
    float c = isq[dst] * isq[src];
    ecr[pos] = make_int2(src, __float_as_int(c));
}

// ---------------- gather: Xa = A_hat x — node-per-wave, ushort2/lane ----------------
__global__ __launch_bounds__(256, 2) void k_gather(
        const ushort2* __restrict__ xb2, const int* __restrict__ rp,
        const int2* __restrict__ ecr, unsigned* __restrict__ Xa){
    __shared__ int   scsr[SCAP];
    __shared__ float scf[SCAP];
    int n0 = blockIdx.x * 4;
    int b0 = rp[n0];
    int tot  = rp[n0 + 4] - b0;
    int stot = min(tot, SCAP);
    for (int i = threadIdx.x; i < stot; i += 256){
        int2 ev = ecr[b0 + i];
        scsr[i] = ev.x;
        scf[i]  = __int_as_float(ev.y);
    }
    __syncthreads();

    int w = threadIdx.x >> 6, l = threadIdx.x & 63;
    int n = n0 + w;
    float a0 = 0.f, a1 = 0.f;
    int b = rp[n] - b0, e = rp[n + 1] - b0;
    int elim = min(e, stot);
    #pragma unroll 4
    for (int i = b; i < elim; ++i){
        int s = scsr[i];
        float c = scf[i];
        ushort2 v = xb2[(size_t)s * 64 + l];
        a0 += c * __uint_as_float((unsigned)v.x << 16);
        a1 += c * __uint_as_float((unsigned)v.y << 16);
    }
    for (int i = max(b, stot); i < e; ++i){    // fallback (pathological degree)
        int2 ev = ecr[b0 + i];
        float c = __int_as_float(ev.y);
        ushort2 v = xb2[(size_t)ev.x * 64 + l];
        a0 += c * __uint_as_float((unsigned)v.x << 16);
        a1 += c * __uint_as_float((unsigned)v.y << 16);
    }
    Xa[(size_t)n * 64 + l] = packbf(a0, a1);   // features 2l, 2l+1 (row-major, packed)
}

// ---------------- MFMA GEMM 128x128: O = A @ Wp [+b1,relu | interleave] ----------------
template<int EPI>
__global__ __launch_bounds__(512) void k_gemm_mfma(
        const bf16* __restrict__ A, const bf16* __restrict__ Wp,
        const float* __restrict__ vecf, bf16* __restrict__ O){
    int wid  = threadIdx.x >> 6;
    int lane = threadIdx.x & 63;
    int n0 = blockIdx.x * 16;
    int m = lane & 15, q = lane >> 4;

    const bfrag* Ap = (const bfrag*)(A + (size_t)(n0 + m) * 128);
    const bfrag* Bp = (const bfrag*)Wp + (size_t)wid * 256 + lane;

    ffrag c = {0.f, 0.f, 0.f, 0.f};
    #pragma unroll
    for (int kc = 0; kc < 4; ++kc){
        bfrag af = Ap[kc * 4 + q];
        bfrag bf = Bp[kc * 64];
        c = __builtin_amdgcn_mfma_f32_16x16x32_bf16(af, bf, c, 0, 0, 0);
    }
    __syncthreads();                      // all A reads done -> in-place stores safe

    int col = wid * 16 + m;
    if (EPI == 0){
        float bb = vecf[col];             // b1
        #pragma unroll
        for (int r = 0; r < 4; ++r){
            int row = n0 + q * 4 + r;
            O[(size_t)row * 128 + col] = __float2bfloat16(fmaxf(c[r] + bb, 0.f));
        }
    } else {                              // interleaved X2: slot (f*2 + head)
        int f = col & 63, h = col >> 6;
        #pragma unroll
        for (int r = 0; r < 4; ++r){
            int row = n0 + q * 4 + r;
            O[(size_t)row * 128 + f * 2 + h] = __float2bfloat16(c[r]);
        }
    }
}

// ---------------- MFMA GEMM 64x64: Z = Y @ W3p (bf16 out, no bias) ----------------
__global__ __launch_bounds__(256) void k_gemm_z(
        const bf16* __restrict__ Y, const bf16* __restrict__ W3p,
        bf16* __restrict__ Z){
    int wid  = threadIdx.x >> 6;
    int lane = threadIdx.x & 63;
    int n0 = blockIdx.x * 16;
    int m = lane & 15, q = lane >> 4;

    const bfrag* Ap = (const bfrag*)(Y + (size_t)(n0 + m) * 64);
    const bfrag* Bp = (const bfrag*)W3p + (size_t)wid * 128 + lane;

    ffrag c = {0.f, 0.f, 0.f, 0.f};
    #pragma unroll
    for (int kc = 0; kc < 2; ++kc){
        bfrag af = Ap[kc * 4 + q];
        bfrag bf = Bp[kc * 64];
        c = __builtin_amdgcn_mfma_f32_16x16x32_bf16(af, bf, c, 0, 0, 0);
    }
    int col = wid * 16 + m;
    #pragma unroll
    for (int r = 0; r < 4; ++r){
        int row = n0 + q * 4 + r;
        Z[(size_t)row * 64 + col] = __float2bfloat16(c[r]);
    }
}

// ---------------- att logits: per-node wave reduce over interleaved X2 ----------------
__global__ __launch_bounds__(256) void k_att(
        const unsigned* __restrict__ X2u, const float* __restrict__ vecf,
        float2* __restrict__ a_src, float2* __restrict__ a_dst){
    int n = blockIdx.x * 4 + (threadIdx.x >> 6);
    int l = threadIdx.x & 63;
    unsigned v = X2u[(size_t)n * 64 + l];
    float x0 = bfu2f_lo(v), x1 = bfu2f_hi(v);
    float s0 = x0 * vecf[256 + l], s1 = x1 * vecf[320 + l];
    float d0 = x0 * vecf[384 + l], d1 = x1 * vecf[448 + l];
    for (int off = 32; off; off >>= 1){
        s0 += __shfl_down(s0, off, 64);  s1 += __shfl_down(s1, off, 64);
        d0 += __shfl_down(d0, off, 64);  d1 += __shfl_down(d1, off, 64);
    }
    if (l == 0){
        a_src[n] = make_float2(s0, s1);
        a_dst[n] = make_float2(d0, d1);
    }
}

// ---------------- GAT aggregate: two-phase (per-edge exp once, then feature FMA) ----------
__global__ __launch_bounds__(256) void k_gat(
        const unsigned* __restrict__ X2u, const int* __restrict__ rp,
        const int2* __restrict__ ecr, const float2* __restrict__ a_src,
        const float2* __restrict__ a_dst, const float* __restrict__ vecf,
        bf16* __restrict__ Y){
    __shared__ int    scsr[SCAP];
    __shared__ float2 pe[SCAP];
    int n0 = blockIdx.x * 4;
    int b0 = rp[n0];
    int tot  = rp[n0 + 4] - b0;
    int stot = min(tot, SCAP);
    for (int i = threadIdx.x; i < stot; i += 256) scsr[i] = ecr[b0 + i].x;
    __syncthreads();

    int w = threadIdx.x >> 6, f = threadIdx.x & 63;
    int n = n0 + w;
    float2 ad = a_dst[n];
    int b = rp[n] - b0, e = rp[n + 1] - b0;
    int elim = min(e, stot);

    // Phase A: per-edge softmax numerators, one lane per edge
    for (int i = b + f; i < elim; i += 64){
        float2 av = a_src[scsr[i]];
        float e0 = av.x + ad.x, e1 = av.y + ad.y;
        e0 = (e0 > 0.f) ? e0 : 0.2f * e0;              // leaky_relu 0.2
        e1 = (e1 > 0.f) ? e1 : 0.2f * e1;
        pe[i] = make_float2(__expf(e0), __expf(e1));
    }
    // intra-wave LDS write->read; compiler inserts lgkmcnt wait (same LDS object)

    // Phase B: feature accumulation (pe[i]/scsr[i] are wave-uniform LDS broadcasts)
    float l0 = 0.f, l1 = 0.f, o0 = 0.f, o1 = 0.f;
    #pragma unroll 4
    for (int i = b; i < elim; ++i){
        float2 p = pe[i];
        unsigned v = X2u[(size_t)scsr[i] * 64 + f];
        l0 += p.x;  o0 += p.x * bfu2f_lo(v);
        l1 += p.y;  o1 += p.y * bfu2f_hi(v);
    }
    for (int i = max(b, stot); i < e; ++i){            // fallback (pathological degree)
        int s = ecr[b0 + i].x;
        float2 av = a_src[s];
        unsigned v = X2u[(size_t)s * 64 + f];
        float e0 = av.x + ad.x, e1 = av.y + ad.y;
        e0 = (e0 > 0.f) ? e0 : 0.2f * e0;
        e1 = (e1 > 0.f) ? e1 : 0.2f * e1;
        float p0 = __expf(e0), p1 = __expf(e1);
        l0 += p0;  o0 += p0 * bfu2f_lo(v);
        l1 += p1;  o1 += p1 * bfu2f_hi(v);
    }
    float val = 0.5f * (o0 / l0 + o1 / l1) + vecf[128 + f];  // bg (self-loop => l>0)
    val = (val > 0.f) ? val : expm1f(val);                    // ELU alpha=1
    Y[(size_t)n * 64 + f] = __float2bfloat16(val);
}

// ---------------- gather_out: out = A_hat Z + b3 (fp32 out) ----------------
__global__ __launch_bounds__(256) void k_gather_out(
        const bf16* __restrict__ Z, const int* __restrict__ rp,
        const int2* __restrict__ ecr, const float* __restrict__ vecf,
        float* __restrict__ out){
    __shared__ int   scsr[SCAP];
    __shared__ float scf[SCAP];
    int n0 = blockIdx.x * 4;
    int b0 = rp[n0];
    int tot  = rp[n0 + 4] - b0;
    int stot = min(tot, SCAP);
    for (int i = threadIdx.x; i < stot; i += 256){
        int2 ev = ecr[b0 + i];
        scsr[i] = ev.x;
        scf[i]  = __int_as_float(ev.y);
    }
    __syncthreads();

    int w = threadIdx.x >> 6, f = threadIdx.x & 63;
    int n = n0 + w;
    float a = vecf[192 + f];                   // b3
    int b = rp[n] - b0, e = rp[n + 1] - b0;
    int elim = min(e, stot);
    #pragma unroll 4
    for (int i = b; i < elim; ++i)
        a += scf[i] * __bfloat162float(Z[(size_t)scsr[i] * 64 + f]);
    for (int i = max(b, stot); i < e; ++i){    // fallback
        int2 ev = ecr[b0 + i];
        a += __int_as_float(ev.y) * __bfloat162float(Z[(size_t)ev.x * 64 + f]);
    }
    out[(size_t)n * 64 + f] = a;
}

// ---------------- launch ----------------

extern "C" void kernel_launch(void* const* d_in, const int* in_sizes, int n_in,
                              void* d_out, int out_size, void* d_ws, size_t ws_size,
                              hipStream_t stream) {
    const void* x  = d_in[0];
    const int*  ei = (const int*)d_in[1];
    float* out = (float*)d_out;

    char* p = (char*)d_ws;
    auto alloc = [&](size_t bytes) -> void* {
        void* r = (void*)p;
        p += (bytes + 255) & ~(size_t)255;
        return r;
    };
    int*   deg      = (int*)  alloc((size_t)N_NODES * 4);
    int*   row_ptr  = (int*)  alloc((size_t)(N_NODES + 1) * 4);
    int*   blk      = (int*)  alloc(256 * 4);
    int*   rank     = (int*)  alloc((size_t)E_TOT * 4);       // 3.4 MB
    int2*  ecr      = (int2*) alloc((size_t)E_TOT * 8);       // 6.8 MB (src+coef interleaved)
    float* inv_sqrt = (float*)alloc((size_t)N_NODES * 4);
    float* a_src    = (float*)alloc((size_t)N_NODES * 2 * 4);
    float* a_dst    = (float*)alloc((size_t)N_NODES * 2 * 4);
    bf16*  W1p      = (bf16*) alloc(16384 * 2);
    bf16*  Wgp      = (bf16*) alloc(16384 * 2);
    bf16*  W3p      = (bf16*) alloc(4096 * 2);
    float* vecf     = (float*)alloc(512 * 4);
    bf16*  xb       = (bf16*) alloc((size_t)N_NODES * 128 * 2);  // 12.8 MB; dead after k_gather
    bf16*  XA       = (bf16*) alloc((size_t)N_NODES * 128 * 2);  // 12.8 MB (Xa -> h1 -> X2)
    bf16*  Y        = (bf16*) alloc((size_t)N_NODES * 64 * 2);   //  6.4 MB
    bf16*  Z        = xb;                                        // alias: Y@W3, layer-3 only
    // total ~44 MB

    const int NB_NODE = (N_NODES + 255) / 256;              // 196
    const int NB_EDGE = (E_TOT + 255) / 256;
    const int NXB     = (N_NODES * 128 + 255) / 256;
    const int NB_CONV = 148 + NXB + NB_NODE;

    k_convert<<<NB_CONV, 256, 0, stream>>>(x, d_in[2], d_in[4], d_in[8],
                                           d_in[3], d_in[7], d_in[9], d_in[5], d_in[6],
                                           W1p, Wgp, W3p, vecf, xb, deg);
    k_count<<<NB_EDGE, 256, 0, stream>>>(ei, deg, rank);
    k_scanA<<<NB_NODE, 256, 0, stream>>>(deg, row_ptr, blk);
    k_scanB<<<1, 256, 0, stream>>>(blk, NB_NODE);
    k_scanC<<<NB_NODE, 256, 0, stream>>>(row_ptr, blk, deg, inv_sqrt);
    k_fill<<<NB_EDGE, 256, 0, stream>>>(ei, row_ptr, inv_sqrt, rank, ecr);

    k_gather<<<N_NODES / 4, 256, 0, stream>>>((const ushort2*)xb, row_ptr, ecr,
                                              (unsigned*)XA);
    k_gemm_mfma<0><<<N_NODES / 16, 512, 0, stream>>>(XA, W1p, vecf, XA);   // h1 = relu(Xa W1 + b1)
    k_gemm_mfma<1><<<N_NODES / 16, 512, 0, stream>>>(XA, Wgp, vecf, XA);   // X2 = h1 Wg (interleaved)
    k_att<<<N_NODES / 4, 256, 0, stream>>>((const unsigned*)XA, vecf, (float2*)a_src, (float2*)a_dst);
    k_gat<<<N_NODES / 4, 256, 0, stream>>>((const unsigned*)XA, row_ptr, ecr,
                                           (const float2*)a_src, (const float2*)a_dst,
                                           vecf, Y);
    k_gemm_z<<<N_NODES / 16, 256, 0, stream>>>(Y, W3p, Z);                 // Z = Y W3
    k_gather_out<<<N_NODES / 4, 256, 0, stream>>>(Z, row_ptr, ecr, vecf, out);
}

// Round 2
// 289.872 us; speedup vs baseline: 1.1542x; 1.0760x over previous
//
#include <hip/hip_runtime.h>
#include <hip/hip_bf16.h>
#include <math.h>

#define N_NODES 50000
#define E0      800000
#define E_TOT   (E0 + N_NODES)
#define SCAP    512

using bf16 = __hip_bfloat16;
typedef __attribute__((ext_vector_type(8))) short bfrag;   // 8 bf16 (4 VGPRs)
typedef __attribute__((ext_vector_type(4))) float ffrag;   // 4 fp32 acc

static __device__ __forceinline__ float bfu2f_lo(unsigned u){ return __uint_as_float(u << 16); }
static __device__ __forceinline__ float bfu2f_hi(unsigned u){ return __uint_as_float(u & 0xffff0000u); }
static __device__ __forceinline__ float us2f(unsigned short u){ return __uint_as_float((unsigned)u << 16); }

static __device__ __forceinline__ unsigned packbf(float a, float b){
    bf16 x = __float2bfloat16(a), y = __float2bfloat16(b);
    unsigned short ux = *reinterpret_cast<unsigned short*>(&x);
    unsigned short uy = *reinterpret_cast<unsigned short*>(&y);
    return ((unsigned)uy << 16) | ux;
}

// per-wave dtype detects (one coalesced load + ballot)
static __device__ __forceinline__ int detect_f32(const unsigned* xu){
    int lane = threadIdx.x & 63;
    unsigned ex = (xu[lane] >> 7) & 0xFF;
    return (__ballot(ex < 100 || ex > 140) != 0ULL);
}
static __device__ __forceinline__ int detect_i32(const int* ei){
    int lane = threadIdx.x & 63;
    return (__ballot(ei[2 * lane + 1] != 0) != 0ULL);
}

static __device__ __forceinline__ float ldany(const void* p, int i, int isf32){
    return isf32 ? ((const float*)p)[i] : __bfloat162float(((const bf16*)p)[i]);
}

// ---------------- convert: W1/Wg/W3 -> packed bf16 MFMA frags, vecs->fp32,
// x->bf16, zero deg — one grid.
// vecf: b1 @0(128), bg @128(64), b3 @192(64), att_s @256(128), att_d @384(128)
__global__ void k_convert(const void* __restrict__ xv,
                          const void* W1, const void* Wg, const void* W3,
                          const void* b1, const void* bg, const void* b3,
                          const void* as_, const void* ad_,
                          bf16* __restrict__ W1p, bf16* __restrict__ Wgp,
                          bf16* __restrict__ W3p, float* __restrict__ vecf,
                          bf16* __restrict__ xb, int* __restrict__ deg){
    const int NXB = (N_NODES * 128 + 255) / 256;
    int b = blockIdx.x, t = threadIdx.x;
    if (b >= 148 + NXB){
        int i = (b - 148 - NXB) * 256 + t;
        if (i < N_NODES) deg[i] = 0;
        return;
    }
    int isf = detect_f32((const unsigned*)xv);
    if (b >= 148){
        int i = (b - 148) * 256 + t;
        if (i < N_NODES * 128) xb[i] = __float2bfloat16(ldany(xv, i, isf));
        return;
    }
    if (b < 16){                              // W3 pack: 4096 elems
        int dd = b * 256 + t;
        int j  = dd & 7;
        int L  = (dd >> 3) & 63;
        int kc = (dd >> 9) & 1;
        int ct = dd >> 10;
        int k = kc * 32 + ((L >> 4) << 3) + j;
        int n = ct * 16 + (L & 15);
        W3p[dd] = __float2bfloat16(ldany(W3, k * 64 + n, isf));
    }
    else if (b < 18){
        int i = (b - 16) * 256 + t;     // 0..511
        float v;
        if      (i < 128) v = ldany(b1,  i,       isf);
        else if (i < 192) v = ldany(bg,  i - 128, isf);
        else if (i < 256) v = ldany(b3,  i - 192, isf);
        else if (i < 384) v = ldany(as_, i - 256, isf);
        else              v = ldany(ad_, i - 384, isf);
        vecf[i] = v;
    } else {
        int d = (b - 18) * 256 + t;          // 0..16383 per W, two Ws
        const void* Wsrc = (d < 16384) ? W1 : Wg;
        bf16* Wdst = (d < 16384) ? W1p : Wgp;
        int dd = d & 16383;
        int j  = dd & 7;
        int L  = (dd >> 3) & 63;
        int kc = (dd >> 9) & 3;
        int ct = dd >> 11;
        int k = kc * 32 + ((L >> 4) << 3) + j;
        int n = ct * 16 + (L & 15);
        Wdst[dd] = __float2bfloat16(ldany(Wsrc, k * 128 + n, isf));
    }
}

// ---------------- CSR build ----------------

static __device__ __forceinline__ int load_dst(const int* ei, int e, int is32){
    if (e >= E0) return e - E0;
    return is32 ? ei[E0 + e] : (int)((const long long*)ei)[E0 + e];
}
static __device__ __forceinline__ int load_src(const int* ei, int e, int is32){
    if (e >= E0) return e - E0;
    return is32 ? ei[e] : (int)((const long long*)ei)[e];
}

// count degrees AND capture each edge's rank within its dst bucket (streaming store).
__global__ void k_count(const int* __restrict__ ei, int* __restrict__ deg,
                        int* __restrict__ rank){
    int is32 = detect_i32(ei);
    int e = blockIdx.x * blockDim.x + threadIdx.x;
    if (e >= E_TOT) return;
    int dst = load_dst(ei, e, is32);
    int src = load_src(ei, e, is32);
    if ((unsigned)dst >= N_NODES || (unsigned)src >= N_NODES) return;
    rank[e] = atomicAdd(&deg[dst], 1);
}

__global__ void k_scanA(const int* __restrict__ deg, int* __restrict__ tmp, int* __restrict__ blk){
    __shared__ int s[256];
    int t = threadIdx.x;
    int i = blockIdx.x * 256 + t;
    int v = (i < N_NODES) ? deg[i] : 0;
    s[t] = v; __syncthreads();
    for (int off = 1; off < 256; off <<= 1){
        int x = (t >= off) ? s[t - off] : 0;
        __syncthreads();
        s[t] += x;
        __syncthreads();
    }
    if (t == 255) blk[blockIdx.x] = s[255];
    if (i < N_NODES) tmp[i] = s[t] - v;
}

// scanC with inlined cross-block prefix (each block reduces blk[0..B-1] itself)
__global__ void k_scanC(int* __restrict__ row_ptr, const int* __restrict__ blk,
                        const int* __restrict__ deg, float* __restrict__ inv_sqrt,
                        int nb){
    __shared__ int s[256];
    int t = threadIdx.x;
    int B = blockIdx.x;
    s[t] = (t < nb && t < B) ? blk[t] : 0;
    __syncthreads();
    for (int off = 128; off; off >>= 1){
        if (t < off) s[t] += s[t + off];
        __syncthreads();
    }
    int base = s[0];
    int i = B * 256 + t;
    if (i < N_NODES){
        row_ptr[i] += base;
        int d = deg[i];
        inv_sqrt[i] = (d > 0) ? rsqrtf((float)d) : 0.0f;
    }
    if (i == 0) row_ptr[N_NODES] = E_TOT;
}

// fill: NO atomics; ONE scattered 8B store per edge (src + coef packed as int2)
__global__ void k_fill(const int* __restrict__ ei, const int* __restrict__ row_ptr,
                       const float* __restrict__ isq, const int* __restrict__ rank,
                       int2* __restrict__ ecr){
    int is32 = detect_i32(ei);
    int e = blockIdx.x * blockDim.x + threadIdx.x;
    if (e >= E_TOT) return;
    int dst = load_dst(ei, e, is32);
    int src = load_src(ei, e, is32);
    if ((unsigned)dst >= N_NODES || (unsigned)src >= N_NODES) return;
    int pos = row_ptr[dst] + rank[e];
    float c = isq[dst] * isq[src];
    ecr[pos] = make_int2(src, __float_as_int(c));
}

// ---------------- gather: Xa = A_hat x — split-half wave: lanes 0-31 even edges,
// lanes 32-63 odd edges; each lane covers 4 features via ushort4. Halves the serial
// dependent-load chain and doubles loads-in-flight.
__global__ __launch_bounds__(256, 2) void k_gather(
        const ushort4* __restrict__ xb4, const int* __restrict__ rp,
        const int2* __restrict__ ecr, uint2* __restrict__ Xa){
    __shared__ int   scsr[SCAP];
    __shared__ float scf[SCAP];
    int n0 = blockIdx.x * 4;
    int b0 = rp[n0];
    int tot  = rp[n0 + 4] - b0;
    int stot = min(tot, SCAP);
    for (int i = threadIdx.x; i < stot; i += 256){
        int2 ev = ecr[b0 + i];
        scsr[i] = ev.x;
        scf[i]  = __int_as_float(ev.y);
    }
    __syncthreads();

    int w    = threadIdx.x >> 6;
    int half = (threadIdx.x >> 5) & 1;
    int fz   = threadIdx.x & 31;
    int n = n0 + w;
    float a0 = 0.f, a1 = 0.f, a2 = 0.f, a3 = 0.f;
    int b = rp[n] - b0, e = rp[n + 1] - b0;
    int elim = min(e, stot);
    #pragma unroll 4
    for (int i = b + half; i < elim; i += 2){
        int s = scsr[i];
        float c = scf[i];
        ushort4 v = xb4[(size_t)s * 32 + fz];
        a0 += c * us2f(v.x);  a1 += c * us2f(v.y);
        a2 += c * us2f(v.z);  a3 += c * us2f(v.w);
    }
    int start = max(b, stot);
    int i0 = start + (((b + half) ^ start) & 1);      // keep parity i ≡ b+half (mod 2)
    for (int i = i0; i < e; i += 2){                  // fallback (pathological degree)
        int2 ev = ecr[b0 + i];
        float c = __int_as_float(ev.y);
        ushort4 v = xb4[(size_t)ev.x * 32 + fz];
        a0 += c * us2f(v.x);  a1 += c * us2f(v.y);
        a2 += c * us2f(v.z);  a3 += c * us2f(v.w);
    }
    a0 += __shfl_xor(a0, 32, 64);  a1 += __shfl_xor(a1, 32, 64);
    a2 += __shfl_xor(a2, 32, 64);  a3 += __shfl_xor(a3, 32, 64);
    if (half == 0)
        Xa[(size_t)n * 32 + fz] = make_uint2(packbf(a0, a1), packbf(a2, a3));
}

// ---------------- MFMA GEMM 128x128: O = A @ Wp.
// EPI==0: +b1, relu.  EPI==1: interleaved X2 store + FUSED att logits
// (a_src/a_dst) via cross-m shfl reduce + 1KB LDS cross-wave reduce.
template<int EPI>
__global__ __launch_bounds__(512) void k_gemm_mfma(
        const bf16* __restrict__ A, const bf16* __restrict__ Wp,
        const float* __restrict__ vecf, bf16* __restrict__ O,
        float* __restrict__ aS, float* __restrict__ aD){
    __shared__ float sA[16][8];
    __shared__ float sD[16][8];
    int wid  = threadIdx.x >> 6;
    int lane = threadIdx.x & 63;
    int n0 = blockIdx.x * 16;
    int m = lane & 15, q = lane >> 4;

    const bfrag* Ap = (const bfrag*)(A + (size_t)(n0 + m) * 128);
    const bfrag* Bp = (const bfrag*)Wp + (size_t)wid * 256 + lane;

    ffrag c = {0.f, 0.f, 0.f, 0.f};
    #pragma unroll
    for (int kc = 0; kc < 4; ++kc){
        bfrag af = Ap[kc * 4 + q];
        bfrag bf = Bp[kc * 64];
        c = __builtin_amdgcn_mfma_f32_16x16x32_bf16(af, bf, c, 0, 0, 0);
    }
    __syncthreads();                      // all A reads done -> in-place stores safe

    int col = wid * 16 + m;
    if (EPI == 0){
        float bb = vecf[col];             // b1
        #pragma unroll
        for (int r = 0; r < 4; ++r){
            int row = n0 + q * 4 + r;
            O[(size_t)row * 128 + col] = __float2bfloat16(fmaxf(c[r] + bb, 0.f));
        }
    } else {                              // interleaved X2: slot (f*2 + head)
        int f = col & 63, h = col >> 6;
        float as_v = vecf[256 + h * 64 + f];
        float ad_v = vecf[384 + h * 64 + f];
        float ps[4], pd[4];
        #pragma unroll
        for (int r = 0; r < 4; ++r){
            int row = n0 + q * 4 + r;
            O[(size_t)row * 128 + f * 2 + h] = __float2bfloat16(c[r]);
            ps[r] = c[r] * as_v;
            pd[r] = c[r] * ad_v;
        }
        #pragma unroll
        for (int off = 1; off < 16; off <<= 1){
            #pragma unroll
            for (int r = 0; r < 4; ++r){
                ps[r] += __shfl_xor(ps[r], off, 64);
                pd[r] += __shfl_xor(pd[r], off, 64);
            }
        }
        if (m == 0){
            #pragma unroll
            for (int r = 0; r < 4; ++r){
                int rl = q * 4 + r;
                sA[rl][wid] = ps[r];
                sD[rl][wid] = pd[r];
            }
        }
        __syncthreads();
        int t = threadIdx.x;
        if (t < 64){
            int rl = t >> 2, hh = (t >> 1) & 1, which = t & 1;
            const float (*S)[8] = which ? sD : sA;
            float v = S[rl][hh * 4 + 0] + S[rl][hh * 4 + 1]
                    + S[rl][hh * 4 + 2] + S[rl][hh * 4 + 3];
            float* dp = which ? aD : aS;
            dp[(size_t)(n0 + rl) * 2 + hh] = v;
        }
    }
}

// ---------------- MFMA GEMM 64x64: Z = Y @ W3p (bf16 out, no bias) ----------------
__global__ __launch_bounds__(256) void k_gemm_z(
        const bf16* __restrict__ Y, const bf16* __restrict__ W3p,
        bf16* __restrict__ Z){
    int wid  = threadIdx.x >> 6;
    int lane = threadIdx.x & 63;
    int n0 = blockIdx.x * 16;
    int m = lane & 15, q = lane >> 4;

    const bfrag* Ap = (const bfrag*)(Y + (size_t)(n0 + m) * 64);
    const bfrag* Bp = (const bfrag*)W3p + (size_t)wid * 128 + lane;

    ffrag c = {0.f, 0.f, 0.f, 0.f};
    #pragma unroll
    for (int kc = 0; kc < 2; ++kc){
        bfrag af = Ap[kc * 4 + q];
        bfrag bf = Bp[kc * 64];
        c = __builtin_amdgcn_mfma_f32_16x16x32_bf16(af, bf, c, 0, 0, 0);
    }
    int col = wid * 16 + m;
    #pragma unroll
    for (int r = 0; r < 4; ++r){
        int row = n0 + q * 4 + r;
        Z[(size_t)row * 64 + col] = __float2bfloat16(c[r]);
    }
}

// ---------------- GAT aggregate: phase A (per-edge exp, lane-strided) ->
// phase B split-half (uint2 loads, 2 edges in flight) ----------------
__global__ __launch_bounds__(256) void k_gat(
        const uint2* __restrict__ X2u2, const int* __restrict__ rp,
        const int2* __restrict__ ecr, const float2* __restrict__ a_src,
        const float2* __restrict__ a_dst, const float* __restrict__ vecf,
        unsigned* __restrict__ Yu){
    __shared__ int    scsr[SCAP];
    __shared__ float2 pe[SCAP];
    int n0 = blockIdx.x * 4;
    int b0 = rp[n0];
    int tot  = rp[n0 + 4] - b0;
    int stot = min(tot, SCAP);
    for (int i = threadIdx.x; i < stot; i += 256) scsr[i] = ecr[b0 + i].x;
    __syncthreads();

    int w    = threadIdx.x >> 6;
    int f    = threadIdx.x & 63;
    int half = (threadIdx.x >> 5) & 1;
    int fz   = threadIdx.x & 31;
    int n = n0 + w;
    float2 ad = a_dst[n];
    int b = rp[n] - b0, e = rp[n + 1] - b0;
    int elim = min(e, stot);

    // Phase A: per-edge softmax numerators, one lane per edge
    for (int i = b + f; i < elim; i += 64){
        float2 av = a_src[scsr[i]];
        float e0 = av.x + ad.x, e1 = av.y + ad.y;
        e0 = (e0 > 0.f) ? e0 : 0.2f * e0;              // leaky_relu 0.2
        e1 = (e1 > 0.f) ? e1 : 0.2f * e1;
        pe[i] = make_float2(__expf(e0), __expf(e1));
    }
    // intra-wave LDS write->read; compiler inserts lgkmcnt wait (same LDS object)

    // Phase B: split-half feature accumulation
    float l0 = 0.f, l1 = 0.f;
    float o00 = 0.f, o01 = 0.f, o10 = 0.f, o11 = 0.f;
    #pragma unroll 4
    for (int i = b + half; i < elim; i += 2){
        float2 p = pe[i];
        uint2 v = X2u2[(size_t)scsr[i] * 32 + fz];
        l0  += p.x;                 l1  += p.y;
        o00 += p.x * bfu2f_lo(v.x); o01 += p.y * bfu2f_hi(v.x);
        o10 += p.x * bfu2f_lo(v.y); o11 += p.y * bfu2f_hi(v.y);
    }
    int start = max(b, stot);
    int i0 = start + (((b + half) ^ start) & 1);
    for (int i = i0; i < e; i += 2){                   // fallback (pathological degree)
        int s = ecr[b0 + i].x;
        float2 av = a_src[s];
        uint2 v = X2u2[(size_t)s * 32 + fz];
        float e0 = av.x + ad.x, e1 = av.y + ad.y;
        e0 = (e0 > 0.f) ? e0 : 0.2f * e0;
        e1 = (e1 > 0.f) ? e1 : 0.2f * e1;
        float p0 = __expf(e0), p1 = __expf(e1);
        l0  += p0;                 l1  += p1;
        o00 += p0 * bfu2f_lo(v.x); o01 += p1 * bfu2f_hi(v.x);
        o10 += p0 * bfu2f_lo(v.y); o11 += p1 * bfu2f_hi(v.y);
    }
    l0  += __shfl_xor(l0, 32, 64);   l1  += __shfl_xor(l1, 32, 64);
    o00 += __shfl_xor(o00, 32, 64);  o01 += __shfl_xor(o01, 32, 64);
    o10 += __shfl_xor(o10, 32, 64);  o11 += __shfl_xor(o11, 32, 64);
    if (half == 0){
        float v0 = 0.5f * (o00 / l0 + o01 / l1) + vecf[128 + 2 * fz];
        float v1 = 0.5f * (o10 / l0 + o11 / l1) + vecf[128 + 2 * fz + 1];
        v0 = (v0 > 0.f) ? v0 : expm1f(v0);             // ELU alpha=1
        v1 = (v1 > 0.f) ? v1 : expm1f(v1);
        Yu[(size_t)n * 32 + fz] = packbf(v0, v1);
    }
}

// ---------------- gather_out: out = A_hat Z + b3 — split-half, uint loads ----------------
__global__ __launch_bounds__(256) void k_gather_out(
        const unsigned* __restrict__ Zu, const int* __restrict__ rp,
        const int2* __restrict__ ecr, const float* __restrict__ vecf,
        float2* __restrict__ out2){
    __shared__ int   scsr[SCAP];
    __shared__ float scf[SCAP];
    int n0 = blockIdx.x * 4;
    int b0 = rp[n0];
    int tot  = rp[n0 + 4] - b0;
    int stot = min(tot, SCAP);
    for (int i = threadIdx.x; i < stot; i += 256){
        int2 ev = ecr[b0 + i];
        scsr[i] = ev.x;
        scf[i]  = __int_as_float(ev.y);
    }
    __syncthreads();

    int w    = threadIdx.x >> 6;
    int half = (threadIdx.x >> 5) & 1;
    int fz   = threadIdx.x & 31;
    int n = n0 + w;
    float a0 = 0.f, a1 = 0.f;
    int b = rp[n] - b0, e = rp[n + 1] - b0;
    int elim = min(e, stot);
    #pragma unroll 4
    for (int i = b + half; i < elim; i += 2){
        float c = scf[i];
        unsigned v = Zu[(size_t)scsr[i] * 32 + fz];
        a0 += c * bfu2f_lo(v);
        a1 += c * bfu2f_hi(v);
    }
    int start = max(b, stot);
    int i0 = start + (((b + half) ^ start) & 1);
    for (int i = i0; i < e; i += 2){                   // fallback
        int2 ev = ecr[b0 + i];
        float c = __int_as_float(ev.y);
        unsigned v = Zu[(size_t)ev.x * 32 + fz];
        a0 += c * bfu2f_lo(v);
        a1 += c * bfu2f_hi(v);
    }
    a0 += __shfl_xor(a0, 32, 64);
    a1 += __shfl_xor(a1, 32, 64);
    if (half == 0)
        out2[(size_t)n * 32 + fz] =
            make_float2(a0 + vecf[192 + 2 * fz], a1 + vecf[192 + 2 * fz + 1]);
}

// ---------------- launch ----------------

extern "C" void kernel_launch(void* const* d_in, const int* in_sizes, int n_in,
                              void* d_out, int out_size, void* d_ws, size_t ws_size,
                              hipStream_t stream) {
    const void* x  = d_in[0];
    const int*  ei = (const int*)d_in[1];
    float* out = (float*)d_out;

    char* p = (char*)d_ws;
    auto alloc = [&](size_t bytes) -> void* {
        void* r = (void*)p;
        p += (bytes + 255) & ~(size_t)255;
        return r;
    };
    int*   deg      = (int*)  alloc((size_t)N_NODES * 4);
    int*   row_ptr  = (int*)  alloc((size_t)(N_NODES + 1) * 4);
    int*   blk      = (int*)  alloc(256 * 4);
    int*   rank     = (int*)  alloc((size_t)E_TOT * 4);       // 3.4 MB
    int2*  ecr      = (int2*) alloc((size_t)E_TOT * 8);       // 6.8 MB (src+coef interleaved)
    float* inv_sqrt = (float*)alloc((size_t)N_NODES * 4);
    float* a_src    = (float*)alloc((size_t)N_NODES * 2 * 4);
    float* a_dst    = (float*)alloc((size_t)N_NODES * 2 * 4);
    bf16*  W1p      = (bf16*) alloc(16384 * 2);
    bf16*  Wgp      = (bf16*) alloc(16384 * 2);
    bf16*  W3p      = (bf16*) alloc(4096 * 2);
    float* vecf     = (float*)alloc(512 * 4);
    bf16*  xb       = (bf16*) alloc((size_t)N_NODES * 128 * 2);  // 12.8 MB; dead after k_gather
    bf16*  XA       = (bf16*) alloc((size_t)N_NODES * 128 * 2);  // 12.8 MB (Xa -> h1 -> X2)
    bf16*  Y        = (bf16*) alloc((size_t)N_NODES * 64 * 2);   //  6.4 MB
    bf16*  Z        = xb;                                        // alias: Y@W3, layer-3 only

    const int NB_NODE = (N_NODES + 255) / 256;              // 196
    const int NB_EDGE = (E_TOT + 255) / 256;
    const int NXB     = (N_NODES * 128 + 255) / 256;
    const int NB_CONV = 148 + NXB + NB_NODE;

    k_convert<<<NB_CONV, 256, 0, stream>>>(x, d_in[2], d_in[4], d_in[8],
                                           d_in[3], d_in[7], d_in[9], d_in[5], d_in[6],
                                           W1p, Wgp, W3p, vecf, xb, deg);
    k_count<<<NB_EDGE, 256, 0, stream>>>(ei, deg, rank);
    k_scanA<<<NB_NODE, 256, 0, stream>>>(deg, row_ptr, blk);
    k_scanC<<<NB_NODE, 256, 0, stream>>>(row_ptr, blk, deg, inv_sqrt, NB_NODE);
    k_fill<<<NB_EDGE, 256, 0, stream>>>(ei, row_ptr, inv_sqrt, rank, ecr);

    k_gather<<<N_NODES / 4, 256, 0, stream>>>((const ushort4*)xb, row_ptr, ecr,
                                              (uint2*)XA);
    k_gemm_mfma<0><<<N_NODES / 16, 512, 0, stream>>>(XA, W1p, vecf, XA,
                                                     nullptr, nullptr);      // h1 = relu(Xa W1 + b1)
    k_gemm_mfma<1><<<N_NODES / 16, 512, 0, stream>>>(XA, Wgp, vecf, XA,
                                                     a_src, a_dst);          // X2 + att logits
    k_gat<<<N_NODES / 4, 256, 0, stream>>>((const uint2*)XA, row_ptr, ecr,
                                           (const float2*)a_src, (const float2*)a_dst,
                                           vecf, (unsigned*)Y);
    k_gemm_z<<<N_NODES / 16, 256, 0, stream>>>(Y, W3p, Z);                   // Z = Y W3
    k_gather_out<<<N_NODES / 4, 256, 0, stream>>>((const unsigned*)Z, row_ptr, ecr,
                                                  vecf, (float2*)out);
}

// Round 3
// 285.427 us; speedup vs baseline: 1.1722x; 1.0156x over previous
//
#include <hip/hip_runtime.h>
#include <hip/hip_bf16.h>
#include <math.h>

#define N_NODES 50000
#define E0      800000
#define E_TOT   (E0 + N_NODES)
#define SCAP    512

using bf16 = __hip_bfloat16;
typedef __attribute__((ext_vector_type(8))) short bfrag;   // 8 bf16 (4 VGPRs)
typedef __attribute__((ext_vector_type(4))) float ffrag;   // 4 fp32 acc

static __device__ __forceinline__ float bfu2f_lo(unsigned u){ return __uint_as_float(u << 16); }
static __device__ __forceinline__ float bfu2f_hi(unsigned u){ return __uint_as_float(u & 0xffff0000u); }

static __device__ __forceinline__ unsigned packbf(float a, float b){
    bf16 x = __float2bfloat16(a), y = __float2bfloat16(b);
    unsigned short ux = *reinterpret_cast<unsigned short*>(&x);
    unsigned short uy = *reinterpret_cast<unsigned short*>(&y);
    return ((unsigned)uy << 16) | ux;
}

// per-wave dtype detects (one coalesced load + ballot)
static __device__ __forceinline__ int detect_f32(const unsigned* xu){
    int lane = threadIdx.x & 63;
    unsigned ex = (xu[lane] >> 7) & 0xFF;
    return (__ballot(ex < 100 || ex > 140) != 0ULL);
}
static __device__ __forceinline__ int detect_i32(const int* ei){
    int lane = threadIdx.x & 63;
    return (__ballot(ei[2 * lane + 1] != 0) != 0ULL);
}

static __device__ __forceinline__ float ldany(const void* p, int i, int isf32){
    return isf32 ? ((const float*)p)[i] : __bfloat162float(((const bf16*)p)[i]);
}

// ---------------- convert: W1/Wg/W3 -> packed bf16 MFMA frags, vecs->fp32,
// x->bf16 (vectorized 4/thread), zero deg — one grid.
// vecf: b1 @0(128), bg @128(64), b3 @192(64), att_s @256(128), att_d @384(128)
__global__ void k_convert(const void* __restrict__ xv,
                          const void* W1, const void* Wg, const void* W3,
                          const void* b1, const void* bg, const void* b3,
                          const void* as_, const void* ad_,
                          bf16* __restrict__ W1p, bf16* __restrict__ Wgp,
                          bf16* __restrict__ W3p, float* __restrict__ vecf,
                          bf16* __restrict__ xb, int* __restrict__ deg){
    const int NXB = (N_NODES * 32 + 255) / 256;   // 4 elems / thread
    int b = blockIdx.x, t = threadIdx.x;
    if (b >= 148 + NXB){
        int i = (b - 148 - NXB) * 256 + t;
        if (i < N_NODES) deg[i] = 0;
        return;
    }
    int isf = detect_f32((const unsigned*)xv);
    if (b >= 148){
        int i = (b - 148) * 256 + t;               // quad index
        if (i < N_NODES * 32){
            if (isf){
                float4 v = ((const float4*)xv)[i];
                ((uint2*)xb)[i] = make_uint2(packbf(v.x, v.y), packbf(v.z, v.w));
            } else {
                ((uint2*)xb)[i] = ((const uint2*)xv)[i];   // already bf16: copy
            }
        }
        return;
    }
    if (b < 16){                              // W3 pack: 4096 elems
        int dd = b * 256 + t;
        int j  = dd & 7;
        int L  = (dd >> 3) & 63;
        int kc = (dd >> 9) & 1;
        int ct = dd >> 10;
        int k = kc * 32 + ((L >> 4) << 3) + j;
        int n = ct * 16 + (L & 15);
        W3p[dd] = __float2bfloat16(ldany(W3, k * 64 + n, isf));
    }
    else if (b < 18){
        int i = (b - 16) * 256 + t;     // 0..511
        float v;
        if      (i < 128) v = ldany(b1,  i,       isf);
        else if (i < 192) v = ldany(bg,  i - 128, isf);
        else if (i < 256) v = ldany(b3,  i - 192, isf);
        else if (i < 384) v = ldany(as_, i - 256, isf);
        else              v = ldany(ad_, i - 384, isf);
        vecf[i] = v;
    } else {
        int d = (b - 18) * 256 + t;          // 0..16383 per W, two Ws
        const void* Wsrc = (d < 16384) ? W1 : Wg;
        bf16* Wdst = (d < 16384) ? W1p : Wgp;
        int dd = d & 16383;
        int j  = dd & 7;
        int L  = (dd >> 3) & 63;
        int kc = (dd >> 9) & 3;
        int ct = dd >> 11;
        int k = kc * 32 + ((L >> 4) << 3) + j;
        int n = ct * 16 + (L & 15);
        Wdst[dd] = __float2bfloat16(ldany(Wsrc, k * 128 + n, isf));
    }
}

// ---------------- CSR build ----------------

static __device__ __forceinline__ int load_dst(const int* ei, int e, int is32){
    if (e >= E0) return e - E0;
    return is32 ? ei[E0 + e] : (int)((const long long*)ei)[E0 + e];
}
static __device__ __forceinline__ int load_src(const int* ei, int e, int is32){
    if (e >= E0) return e - E0;
    return is32 ? ei[e] : (int)((const long long*)ei)[e];
}

// count degrees AND capture each edge's rank within its dst bucket (streaming store).
__global__ void k_count(const int* __restrict__ ei, int* __restrict__ deg,
                        int* __restrict__ rank){
    int is32 = detect_i32(ei);
    int e = blockIdx.x * blockDim.x + threadIdx.x;
    if (e >= E_TOT) return;
    int dst = load_dst(ei, e, is32);
    int src = load_src(ei, e, is32);
    if ((unsigned)dst >= N_NODES || (unsigned)src >= N_NODES) return;
    rank[e] = atomicAdd(&deg[dst], 1);
}

__global__ void k_scanA(const int* __restrict__ deg, int* __restrict__ tmp, int* __restrict__ blk){
    __shared__ int s[256];
    int t = threadIdx.x;
    int i = blockIdx.x * 256 + t;
    int v = (i < N_NODES) ? deg[i] : 0;
    s[t] = v; __syncthreads();
    for (int off = 1; off < 256; off <<= 1){
        int x = (t >= off) ? s[t - off] : 0;
        __syncthreads();
        s[t] += x;
        __syncthreads();
    }
    if (t == 255) blk[blockIdx.x] = s[255];
    if (i < N_NODES) tmp[i] = s[t] - v;
}

// scanC with inlined cross-block prefix (each block reduces blk[0..B-1] itself)
__global__ void k_scanC(int* __restrict__ row_ptr, const int* __restrict__ blk,
                        const int* __restrict__ deg, float* __restrict__ inv_sqrt,
                        int nb){
    __shared__ int s[256];
    int t = threadIdx.x;
    int B = blockIdx.x;
    s[t] = (t < nb && t < B) ? blk[t] : 0;
    __syncthreads();
    for (int off = 128; off; off >>= 1){
        if (t < off) s[t] += s[t + off];
        __syncthreads();
    }
    int base = s[0];
    int i = B * 256 + t;
    if (i < N_NODES){
        row_ptr[i] += base;
        int d = deg[i];
        inv_sqrt[i] = (d > 0) ? rsqrtf((float)d) : 0.0f;
    }
    if (i == 0) row_ptr[N_NODES] = E_TOT;
}

// fill: NO atomics; ONE scattered 8B store per edge (src + coef packed as int2)
__global__ void k_fill(const int* __restrict__ ei, const int* __restrict__ row_ptr,
                       const float* __restrict__ isq, const int* __restrict__ rank,
                       int2* __restrict__ ecr){
    int is32 = detect_i32(ei);
    int e = blockIdx.x * blockDim.x + threadIdx.x;
    if (e >= E_TOT) return;
    int dst = load_dst(ei, e, is32);
    int src = load_src(ei, e, is32);
    if ((unsigned)dst >= N_NODES || (unsigned)src >= N_NODES) return;
    int pos = row_ptr[dst] + rank[e];
    float c = isq[dst] * isq[src];
    ecr[pos] = make_int2(src, __float_as_int(c));
}

// ---------------- gather: Xa = A_hat x — 4-way split wave: quarter q handles
// edges i ≡ b+q (mod 4); each lane covers 8 features via one uint4 (16B) load.
// Serial chain /4 vs node-per-wave, 4 chains in flight, 16 lanes x 16B = one
// 256B row transaction. Combine via shfl_xor(32)+shfl_xor(16).
__global__ __launch_bounds__(256) void k_gather(
        const uint4* __restrict__ xb16, const int* __restrict__ rp,
        const int2* __restrict__ ecr, uint4* __restrict__ Xa16){
    __shared__ int   scsr[SCAP];
    __shared__ float scf[SCAP];
    int n0 = blockIdx.x * 4;
    int b0 = rp[n0];
    int stot = min(rp[n0 + 4] - b0, SCAP);
    for (int i = threadIdx.x; i < stot; i += 256){
        int2 ev = ecr[b0 + i];
        scsr[i] = ev.x;
        scf[i]  = __int_as_float(ev.y);
    }
    __syncthreads();

    int w = threadIdx.x >> 6, lane = threadIdx.x & 63;
    int q4 = lane >> 4, fz = lane & 15;
    int n = n0 + w;
    float a0=0,a1=0,a2=0,a3=0,a4=0,a5=0,a6=0,a7=0;
    int b = rp[n] - b0, e = rp[n + 1] - b0;
    int elim = min(e, stot);
    #pragma unroll 2
    for (int i = b + q4; i < elim; i += 4){
        int s = scsr[i];
        float c = scf[i];
        uint4 v = xb16[(size_t)s * 16 + fz];
        a0 += c * bfu2f_lo(v.x);  a1 += c * bfu2f_hi(v.x);
        a2 += c * bfu2f_lo(v.y);  a3 += c * bfu2f_hi(v.y);
        a4 += c * bfu2f_lo(v.z);  a5 += c * bfu2f_hi(v.z);
        a6 += c * bfu2f_lo(v.w);  a7 += c * bfu2f_hi(v.w);
    }
    int start = max(b, stot);
    int i0 = start + (((b + q4) - start) & 3);         // keep i ≡ b+q4 (mod 4)
    for (int i = i0; i < e; i += 4){                   // fallback (pathological degree)
        int2 ev = ecr[b0 + i];
        float c = __int_as_float(ev.y);
        uint4 v = xb16[(size_t)ev.x * 16 + fz];
        a0 += c * bfu2f_lo(v.x);  a1 += c * bfu2f_hi(v.x);
        a2 += c * bfu2f_lo(v.y);  a3 += c * bfu2f_hi(v.y);
        a4 += c * bfu2f_lo(v.z);  a5 += c * bfu2f_hi(v.z);
        a6 += c * bfu2f_lo(v.w);  a7 += c * bfu2f_hi(v.w);
    }
    a0 += __shfl_xor(a0, 32, 64);  a0 += __shfl_xor(a0, 16, 64);
    a1 += __shfl_xor(a1, 32, 64);  a1 += __shfl_xor(a1, 16, 64);
    a2 += __shfl_xor(a2, 32, 64);  a2 += __shfl_xor(a2, 16, 64);
    a3 += __shfl_xor(a3, 32, 64);  a3 += __shfl_xor(a3, 16, 64);
    a4 += __shfl_xor(a4, 32, 64);  a4 += __shfl_xor(a4, 16, 64);
    a5 += __shfl_xor(a5, 32, 64);  a5 += __shfl_xor(a5, 16, 64);
    a6 += __shfl_xor(a6, 32, 64);  a6 += __shfl_xor(a6, 16, 64);
    a7 += __shfl_xor(a7, 32, 64);  a7 += __shfl_xor(a7, 16, 64);
    if (lane < 16){
        uint4 o;
        o.x = packbf(a0, a1);  o.y = packbf(a2, a3);
        o.z = packbf(a4, a5);  o.w = packbf(a6, a7);
        Xa16[(size_t)n * 16 + fz] = o;                 // row-major 128 bf16
    }
}

// ---------------- MFMA GEMM 128x128: O = A @ Wp.
// EPI==0: +b1, relu.  EPI==1: interleaved X2 store + FUSED att logits
// (a_src/a_dst) via cross-m shfl reduce + 1KB LDS cross-wave reduce.
template<int EPI>
__global__ __launch_bounds__(512) void k_gemm_mfma(
        const bf16* __restrict__ A, const bf16* __restrict__ Wp,
        const float* __restrict__ vecf, bf16* __restrict__ O,
        float* __restrict__ aS, float* __restrict__ aD){
    __shared__ float sA[16][8];
    __shared__ float sD[16][8];
    int wid  = threadIdx.x >> 6;
    int lane = threadIdx.x & 63;
    int n0 = blockIdx.x * 16;
    int m = lane & 15, q = lane >> 4;

    const bfrag* Ap = (const bfrag*)(A + (size_t)(n0 + m) * 128);
    const bfrag* Bp = (const bfrag*)Wp + (size_t)wid * 256 + lane;

    ffrag c = {0.f, 0.f, 0.f, 0.f};
    #pragma unroll
    for (int kc = 0; kc < 4; ++kc){
        bfrag af = Ap[kc * 4 + q];
        bfrag bf = Bp[kc * 64];
        c = __builtin_amdgcn_mfma_f32_16x16x32_bf16(af, bf, c, 0, 0, 0);
    }
    __syncthreads();                      // all A reads done -> in-place stores safe

    int col = wid * 16 + m;
    if (EPI == 0){
        float bb = vecf[col];             // b1
        #pragma unroll
        for (int r = 0; r < 4; ++r){
            int row = n0 + q * 4 + r;
            O[(size_t)row * 128 + col] = __float2bfloat16(fmaxf(c[r] + bb, 0.f));
        }
    } else {                              // interleaved X2: slot (f*2 + head)
        int f = col & 63, h = col >> 6;
        float as_v = vecf[256 + h * 64 + f];
        float ad_v = vecf[384 + h * 64 + f];
        float ps[4], pd[4];
        #pragma unroll
        for (int r = 0; r < 4; ++r){
            int row = n0 + q * 4 + r;
            O[(size_t)row * 128 + f * 2 + h] = __float2bfloat16(c[r]);
            ps[r] = c[r] * as_v;
            pd[r] = c[r] * ad_v;
        }
        #pragma unroll
        for (int off = 1; off < 16; off <<= 1){
            #pragma unroll
            for (int r = 0; r < 4; ++r){
                ps[r] += __shfl_xor(ps[r], off, 64);
                pd[r] += __shfl_xor(pd[r], off, 64);
            }
        }
        if (m == 0){
            #pragma unroll
            for (int r = 0; r < 4; ++r){
                int rl = q * 4 + r;
                sA[rl][wid] = ps[r];
                sD[rl][wid] = pd[r];
            }
        }
        __syncthreads();
        int t = threadIdx.x;
        if (t < 64){
            int rl = t >> 2, hh = (t >> 1) & 1, which = t & 1;
            const float (*S)[8] = which ? sD : sA;
            float v = S[rl][hh * 4 + 0] + S[rl][hh * 4 + 1]
                    + S[rl][hh * 4 + 2] + S[rl][hh * 4 + 3];
            float* dp = which ? aD : aS;
            dp[(size_t)(n0 + rl) * 2 + hh] = v;
        }
    }
}

// ---------------- MFMA GEMM 64x64: Z = Y @ W3p (bf16 out, no bias) ----------------
__global__ __launch_bounds__(256) void k_gemm_z(
        const bf16* __restrict__ Y, const bf16* __restrict__ W3p,
        bf16* __restrict__ Z){
    int wid  = threadIdx.x >> 6;
    int lane = threadIdx.x & 63;
    int n0 = blockIdx.x * 16;
    int m = lane & 15, q = lane >> 4;

    const bfrag* Ap = (const bfrag*)(Y + (size_t)(n0 + m) * 64);
    const bfrag* Bp = (const bfrag*)W3p + (size_t)wid * 128 + lane;

    ffrag c = {0.f, 0.f, 0.f, 0.f};
    #pragma unroll
    for (int kc = 0; kc < 2; ++kc){
        bfrag af = Ap[kc * 4 + q];
        bfrag bf = Bp[kc * 64];
        c = __builtin_amdgcn_mfma_f32_16x16x32_bf16(af, bf, c, 0, 0, 0);
    }
    int col = wid * 16 + m;
    #pragma unroll
    for (int r = 0; r < 4; ++r){
        int row = n0 + q * 4 + r;
        Z[(size_t)row * 64 + col] = __float2bfloat16(c[r]);
    }
}

// ---------------- GAT aggregate: phase A (per-edge exp, lane-strided) ->
// phase B 4-way split (uint4 16B loads, 4 chains in flight) ----------------
__global__ __launch_bounds__(256) void k_gat(
        const uint4* __restrict__ X2v, const int* __restrict__ rp,
        const int2* __restrict__ ecr, const float2* __restrict__ a_src,
        const float2* __restrict__ a_dst, const float* __restrict__ vecf,
        uint2* __restrict__ Yu2){
    __shared__ int    scsr[SCAP];
    __shared__ float2 pe[SCAP];
    int n0 = blockIdx.x * 4;
    int b0 = rp[n0];
    int stot = min(rp[n0 + 4] - b0, SCAP);
    for (int i = threadIdx.x; i < stot; i += 256) scsr[i] = ecr[b0 + i].x;
    __syncthreads();

    int w = threadIdx.x >> 6, lane = threadIdx.x & 63;
    int q4 = lane >> 4, fz = lane & 15;
    int n = n0 + w;
    float2 ad = a_dst[n];
    int b = rp[n] - b0, e = rp[n + 1] - b0;
    int elim = min(e, stot);

    // Phase A: per-edge softmax numerators, one lane per edge
    for (int i = b + lane; i < elim; i += 64){
        float2 av = a_src[scsr[i]];
        float e0 = av.x + ad.x, e1 = av.y + ad.y;
        e0 = (e0 > 0.f) ? e0 : 0.2f * e0;              // leaky_relu 0.2
        e1 = (e1 > 0.f) ? e1 : 0.2f * e1;
        pe[i] = make_float2(__expf(e0), __expf(e1));
    }
    // intra-wave LDS write->read; compiler inserts lgkmcnt wait (same LDS object)

    // Phase B: 4-way split feature accumulation. X2 slots 8fz..8fz+7 =
    // features 4fz..4fz+3 x heads {0,1} (slot = f*2+h).
    float l0 = 0.f, l1 = 0.f;
    float o00=0,o01=0, o10=0,o11=0, o20=0,o21=0, o30=0,o31=0;   // o{k}{h}, f=4fz+k
    #pragma unroll 2
    for (int i = b + q4; i < elim; i += 4){
        float2 p = pe[i];
        uint4 v = X2v[(size_t)scsr[i] * 16 + fz];
        l0  += p.x;                  l1  += p.y;
        o00 += p.x * bfu2f_lo(v.x);  o01 += p.y * bfu2f_hi(v.x);
        o10 += p.x * bfu2f_lo(v.y);  o11 += p.y * bfu2f_hi(v.y);
        o20 += p.x * bfu2f_lo(v.z);  o21 += p.y * bfu2f_hi(v.z);
        o30 += p.x * bfu2f_lo(v.w);  o31 += p.y * bfu2f_hi(v.w);
    }
    int start = max(b, stot);
    int i0 = start + (((b + q4) - start) & 3);
    for (int i = i0; i < e; i += 4){                   // fallback (pathological degree)
        int s = ecr[b0 + i].x;
        float2 av = a_src[s];
        uint4 v = X2v[(size_t)s * 16 + fz];
        float e0 = av.x + ad.x, e1 = av.y + ad.y;
        e0 = (e0 > 0.f) ? e0 : 0.2f * e0;
        e1 = (e1 > 0.f) ? e1 : 0.2f * e1;
        float p0 = __expf(e0), p1 = __expf(e1);
        l0  += p0;                 l1  += p1;
        o00 += p0 * bfu2f_lo(v.x); o01 += p1 * bfu2f_hi(v.x);
        o10 += p0 * bfu2f_lo(v.y); o11 += p1 * bfu2f_hi(v.y);
        o20 += p0 * bfu2f_lo(v.z); o21 += p1 * bfu2f_hi(v.z);
        o30 += p0 * bfu2f_lo(v.w); o31 += p1 * bfu2f_hi(v.w);
    }
    l0  += __shfl_xor(l0, 32, 64);   l0  += __shfl_xor(l0, 16, 64);
    l1  += __shfl_xor(l1, 32, 64);   l1  += __shfl_xor(l1, 16, 64);
    o00 += __shfl_xor(o00, 32, 64);  o00 += __shfl_xor(o00, 16, 64);
    o01 += __shfl_xor(o01, 32, 64);  o01 += __shfl_xor(o01, 16, 64);
    o10 += __shfl_xor(o10, 32, 64);  o10 += __shfl_xor(o10, 16, 64);
    o11 += __shfl_xor(o11, 32, 64);  o11 += __shfl_xor(o11, 16, 64);
    o20 += __shfl_xor(o20, 32, 64);  o20 += __shfl_xor(o20, 16, 64);
    o21 += __shfl_xor(o21, 32, 64);  o21 += __shfl_xor(o21, 16, 64);
    o30 += __shfl_xor(o30, 32, 64);  o30 += __shfl_xor(o30, 16, 64);
    o31 += __shfl_xor(o31, 32, 64);  o31 += __shfl_xor(o31, 16, 64);
    if (lane < 16){
        float v0 = 0.5f * (o00 / l0 + o01 / l1) + vecf[128 + 4 * fz + 0];
        float v1 = 0.5f * (o10 / l0 + o11 / l1) + vecf[128 + 4 * fz + 1];
        float v2 = 0.5f * (o20 / l0 + o21 / l1) + vecf[128 + 4 * fz + 2];
        float v3 = 0.5f * (o30 / l0 + o31 / l1) + vecf[128 + 4 * fz + 3];
        v0 = (v0 > 0.f) ? v0 : expm1f(v0);             // ELU alpha=1
        v1 = (v1 > 0.f) ? v1 : expm1f(v1);
        v2 = (v2 > 0.f) ? v2 : expm1f(v2);
        v3 = (v3 > 0.f) ? v3 : expm1f(v3);
        Yu2[(size_t)n * 16 + fz] = make_uint2(packbf(v0, v1), packbf(v2, v3));
    }
}

// ---------------- gather_out: out = A_hat Z + b3 — 4-way split, uint2 loads ----------------
__global__ __launch_bounds__(256) void k_gather_out(
        const uint2* __restrict__ Zu2, const int* __restrict__ rp,
        const int2* __restrict__ ecr, const float* __restrict__ vecf,
        float4* __restrict__ out4){
    __shared__ int   scsr[SCAP];
    __shared__ float scf[SCAP];
    int n0 = blockIdx.x * 4;
    int b0 = rp[n0];
    int stot = min(rp[n0 + 4] - b0, SCAP);
    for (int i = threadIdx.x; i < stot; i += 256){
        int2 ev = ecr[b0 + i];
        scsr[i] = ev.x;
        scf[i]  = __int_as_float(ev.y);
    }
    __syncthreads();

    int w = threadIdx.x >> 6, lane = threadIdx.x & 63;
    int q4 = lane >> 4, fz = lane & 15;
    int n = n0 + w;
    float a0 = 0.f, a1 = 0.f, a2 = 0.f, a3 = 0.f;
    int b = rp[n] - b0, e = rp[n + 1] - b0;
    int elim = min(e, stot);
    #pragma unroll 2
    for (int i = b + q4; i < elim; i += 4){
        float c = scf[i];
        uint2 v = Zu2[(size_t)scsr[i] * 16 + fz];
        a0 += c * bfu2f_lo(v.x);  a1 += c * bfu2f_hi(v.x);
        a2 += c * bfu2f_lo(v.y);  a3 += c * bfu2f_hi(v.y);
    }
    int start = max(b, stot);
    int i0 = start + (((b + q4) - start) & 3);
    for (int i = i0; i < e; i += 4){                   // fallback
        int2 ev = ecr[b0 + i];
        float c = __int_as_float(ev.y);
        uint2 v = Zu2[(size_t)ev.x * 16 + fz];
        a0 += c * bfu2f_lo(v.x);  a1 += c * bfu2f_hi(v.x);
        a2 += c * bfu2f_lo(v.y);  a3 += c * bfu2f_hi(v.y);
    }
    a0 += __shfl_xor(a0, 32, 64);  a0 += __shfl_xor(a0, 16, 64);
    a1 += __shfl_xor(a1, 32, 64);  a1 += __shfl_xor(a1, 16, 64);
    a2 += __shfl_xor(a2, 32, 64);  a2 += __shfl_xor(a2, 16, 64);
    a3 += __shfl_xor(a3, 32, 64);  a3 += __shfl_xor(a3, 16, 64);
    if (lane < 16)
        out4[(size_t)n * 16 + fz] = make_float4(
            a0 + vecf[192 + 4 * fz + 0], a1 + vecf[192 + 4 * fz + 1],
            a2 + vecf[192 + 4 * fz + 2], a3 + vecf[192 + 4 * fz + 3]);
}

// ---------------- launch ----------------

extern "C" void kernel_launch(void* const* d_in, const int* in_sizes, int n_in,
                              void* d_out, int out_size, void* d_ws, size_t ws_size,
                              hipStream_t stream) {
    const void* x  = d_in[0];
    const int*  ei = (const int*)d_in[1];
    float* out = (float*)d_out;

    char* p = (char*)d_ws;
    auto alloc = [&](size_t bytes) -> void* {
        void* r = (void*)p;
        p += (bytes + 255) & ~(size_t)255;
        return r;
    };
    int*   deg      = (int*)  alloc((size_t)N_NODES * 4);
    int*   row_ptr  = (int*)  alloc((size_t)(N_NODES + 1) * 4);
    int*   blk      = (int*)  alloc(256 * 4);
    int*   rank     = (int*)  alloc((size_t)E_TOT * 4);       // 3.4 MB
    int2*  ecr      = (int2*) alloc((size_t)E_TOT * 8);       // 6.8 MB (src+coef interleaved)
    float* inv_sqrt = (float*)alloc((size_t)N_NODES * 4);
    float* a_src    = (float*)alloc((size_t)N_NODES * 2 * 4);
    float* a_dst    = (float*)alloc((size_t)N_NODES * 2 * 4);
    bf16*  W1p      = (bf16*) alloc(16384 * 2);
    bf16*  Wgp      = (bf16*) alloc(16384 * 2);
    bf16*  W3p      = (bf16*) alloc(4096 * 2);
    float* vecf     = (float*)alloc(512 * 4);
    bf16*  xb       = (bf16*) alloc((size_t)N_NODES * 128 * 2);  // 12.8 MB; dead after k_gather
    bf16*  XA       = (bf16*) alloc((size_t)N_NODES * 128 * 2);  // 12.8 MB (Xa -> h1 -> X2)
    bf16*  Y        = (bf16*) alloc((size_t)N_NODES * 64 * 2);   //  6.4 MB
    bf16*  Z        = xb;                                        // alias: Y@W3, layer-3 only

    const int NB_NODE = (N_NODES + 255) / 256;              // 196
    const int NB_EDGE = (E_TOT + 255) / 256;
    const int NXB     = (N_NODES * 32 + 255) / 256;         // 6250 (4 elems/thread)
    const int NB_CONV = 148 + NXB + NB_NODE;

    k_convert<<<NB_CONV, 256, 0, stream>>>(x, d_in[2], d_in[4], d_in[8],
                                           d_in[3], d_in[7], d_in[9], d_in[5], d_in[6],
                                           W1p, Wgp, W3p, vecf, xb, deg);
    k_count<<<NB_EDGE, 256, 0, stream>>>(ei, deg, rank);
    k_scanA<<<NB_NODE, 256, 0, stream>>>(deg, row_ptr, blk);
    k_scanC<<<NB_NODE, 256, 0, stream>>>(row_ptr, blk, deg, inv_sqrt, NB_NODE);
    k_fill<<<NB_EDGE, 256, 0, stream>>>(ei, row_ptr, inv_sqrt, rank, ecr);

    k_gather<<<N_NODES / 4, 256, 0, stream>>>((const uint4*)xb, row_ptr, ecr,
                                              (uint4*)XA);
    k_gemm_mfma<0><<<N_NODES / 16, 512, 0, stream>>>(XA, W1p, vecf, XA,
                                                     nullptr, nullptr);      // h1 = relu(Xa W1 + b1)
    k_gemm_mfma<1><<<N_NODES / 16, 512, 0, stream>>>(XA, Wgp, vecf, XA,
                                                     a_src, a_dst);          // X2 + att logits
    k_gat<<<N_NODES / 4, 256, 0, stream>>>((const uint4*)XA, row_ptr, ecr,
                                           (const float2*)a_src, (const float2*)a_dst,
                                           vecf, (uint2*)Y);
    k_gemm_z<<<N_NODES / 16, 256, 0, stream>>>(Y, W3p, Z);                   // Z = Y W3
    k_gather_out<<<N_NODES / 4, 256, 0, stream>>>((const uint2*)Z, row_ptr, ecr,
                                                  vecf, (float4*)out);
}